// Round 6
// baseline (368.278 us; speedup 1.0000x reference)
//
#include <hip/hip_runtime.h>

#define Bz 8
#define Lz 2048
#define Dz 256
#define Nz 64
#define SP 68   // b128-aligned LDS stride (powmm)
#define SA 65   // scalar-access LDS stride (conflict-free rows+cols)
#define KE 8    // Taylor order for E^r / E64 / W (norm(64*dt*A) ~ 0.08)
#define KP 11   // p-chain depth = KE + 3 (dB phi1 terms)

__device__ __forceinline__ float softplusf(float x) {
  return (x > 20.f) ? x : log1pf(expf(x));
}

// ---- power-basis kernels: Apow[k-1] = A^k (row-major 64x64), k=1..8 ----

__global__ __launch_bounds__(256) void s4_powinit(const float* __restrict__ log_A,
                                                  float* __restrict__ Apow) {
  const int i = blockIdx.x * 256 + threadIdx.x;
  Apow[i] = softplusf(log_A[i]);
}

// O(blockIdx) = Apow[li] * Apow[blockIdx]; writes Apow[oi + blockIdx].
__global__ __launch_bounds__(256) void s4_powmm(const float* __restrict__ Apow_c,
                                                float* __restrict__ Apow,
                                                int li, int oi) {
  __shared__ alignas(16) float LA[Nz * SP];
  __shared__ alignas(16) float LB[Nz * SP];
  const int tid = threadIdx.x;
  const float* L = Apow_c + (size_t)li * 4096;
  const float* R = Apow_c + (size_t)blockIdx.x * 4096;
  float* O = Apow + (size_t)(oi + blockIdx.x) * 4096;
#pragma unroll
  for (int i = 0; i < 4; ++i) {
    const int e = (tid + 256 * i) * 4;
    const int r = e >> 6, c = e & 63;
    *(float4*)&LA[r * SP + c] = *(const float4*)(L + e);
    *(float4*)&LB[r * SP + c] = *(const float4*)(R + e);
  }
  __syncthreads();
  const int n = tid & 63, q = tid >> 6;
  float arow[64];
#pragma unroll
  for (int mm = 0; mm < 16; ++mm) {
    const float4 a4 = *(const float4*)(LA + n * SP + mm * 4);
    arow[4 * mm + 0] = a4.x; arow[4 * mm + 1] = a4.y;
    arow[4 * mm + 2] = a4.z; arow[4 * mm + 3] = a4.w;
  }
  float acc[16];
#pragma unroll
  for (int i = 0; i < 16; ++i) acc[i] = 0.f;
#pragma unroll 8
  for (int m = 0; m < 64; ++m) {
    const float4 b0 = *(const float4*)(LB + m * SP + q * 16 + 0);
    const float4 b1 = *(const float4*)(LB + m * SP + q * 16 + 4);
    const float4 b2 = *(const float4*)(LB + m * SP + q * 16 + 8);
    const float4 b3 = *(const float4*)(LB + m * SP + q * 16 + 12);
    const float a = arow[m];
    acc[0]  = fmaf(a, b0.x, acc[0]);  acc[1]  = fmaf(a, b0.y, acc[1]);
    acc[2]  = fmaf(a, b0.z, acc[2]);  acc[3]  = fmaf(a, b0.w, acc[3]);
    acc[4]  = fmaf(a, b1.x, acc[4]);  acc[5]  = fmaf(a, b1.y, acc[5]);
    acc[6]  = fmaf(a, b1.z, acc[6]);  acc[7]  = fmaf(a, b1.w, acc[7]);
    acc[8]  = fmaf(a, b2.x, acc[8]);  acc[9]  = fmaf(a, b2.y, acc[9]);
    acc[10] = fmaf(a, b2.z, acc[10]); acc[11] = fmaf(a, b2.w, acc[11]);
    acc[12] = fmaf(a, b3.x, acc[12]); acc[13] = fmaf(a, b3.y, acc[13]);
    acc[14] = fmaf(a, b3.z, acc[14]); acc[15] = fmaf(a, b3.w, acc[15]);
  }
#pragma unroll
  for (int v = 0; v < 4; ++v) {
    float4 o;
    o.x = acc[4 * v + 0]; o.y = acc[4 * v + 1];
    o.z = acc[4 * v + 2]; o.w = acc[4 * v + 3];
    *(float4*)(O + n * 64 + q * 16 + 4 * v) = o;
  }
}

// ---- per-d build: chained matvecs on shared A, emit small vectors ----
// p_k = A^k Bp_d (k<=KP), q_k = (A^T)^k C_d (k<=KE)
// dB = sum_j dt^{j+1}/(j+1)! p_j ;  g_k = A^k dB = sum_j coef_j p_{k+j}
// kloc[tau] = sum_k ((tau dt)^k/k!) (q_k . dB)
__global__ __launch_bounds__(256) void s4_build2(
    const float* __restrict__ Apow, const float* __restrict__ Bp,
    const float* __restrict__ Cp, const float* __restrict__ log_delta,
    float* __restrict__ Gk, float* __restrict__ Qk,
    float* __restrict__ kloc, float* __restrict__ dts) {
  __shared__ float As[Nz * SA];
  __shared__ float Pst[KP + 1][Nz];
  __shared__ float Qst[KE + 1][Nz];
  __shared__ float Pv[Nz], Qv[Nz], dBs[Nz];
  __shared__ float prA[4][Nz + 8], prB[4][Nz + 8];
  __shared__ float zp[KE + 1][17], zs[KE + 1];
  const int tid = threadIdx.x;
  const int d = blockIdx.x;
  const int n = tid & 63, qq = tid >> 6;
  const float dt = softplusf(log_delta[d]) + 1e-6f;

#pragma unroll
  for (int i = 0; i < 4; ++i) {
    const int e = (tid + 256 * i) * 4;
    const int r = e >> 6, c = e & 63;
    const float4 v = *(const float4*)(Apow + e);
    As[r * SA + c] = v.x; As[r * SA + c + 1] = v.y;
    As[r * SA + c + 2] = v.z; As[r * SA + c + 3] = v.w;
  }
  if (tid < 64) {
    const float bv = Bp[d * Nz + tid], cv = Cp[d * Nz + tid];
    Pv[tid] = bv; Pst[0][tid] = bv;
    Qv[tid] = cv; Qst[0][tid] = cv;
  }
  __syncthreads();
#pragma unroll 1
  for (int k = 1; k <= KP; ++k) {
    float pp = 0.f, pq = 0.f;
#pragma unroll
    for (int mm = 0; mm < 16; ++mm) {
      const int m = qq * 16 + mm;
      pp += As[n * SA + m] * Pv[m];   // (A p)[n]
      pq += As[m * SA + n] * Qv[m];   // (A^T q)[n]
    }
    prA[qq][n] = pp; prB[qq][n] = pq;
    __syncthreads();
    if (tid < 64) {
      const float np = prA[0][tid] + prA[1][tid] + prA[2][tid] + prA[3][tid];
      Pv[tid] = np; Pst[k][tid] = np;
      if (k <= KE) {
        const float nq = prB[0][tid] + prB[1][tid] + prB[2][tid] + prB[3][tid];
        Qv[tid] = nq; Qst[k][tid] = nq;
      }
    }
    __syncthreads();
  }
  const float dtc0 = dt;
  const float dtc1 = dt * dt * 0.5f;
  const float dtc2 = dtc1 * dt * (1.f / 3.f);
  const float dtc3 = dtc2 * dt * 0.25f;
  if (tid < 64) {
    dBs[tid] = dtc0 * Pst[0][tid] + dtc1 * Pst[1][tid] +
               dtc2 * Pst[2][tid] + dtc3 * Pst[3][tid];
#pragma unroll
    for (int k = 0; k <= KE; ++k) {
      Gk[(size_t)d * ((KE + 1) * 64) + k * 64 + tid] =
          dtc0 * Pst[k][tid] + dtc1 * Pst[k + 1][tid] +
          dtc2 * Pst[k + 2][tid] + dtc3 * Pst[k + 3][tid];
      Qk[(size_t)d * ((KE + 1) * 64) + k * 64 + tid] = Qst[k][tid];
    }
  }
  __syncthreads();
  if (tid < (KE + 1) * 16) {
    const int k = tid >> 4, seg = tid & 15;
    float s = 0.f;
#pragma unroll
    for (int i = 0; i < 4; ++i) s += Qst[k][seg * 4 + i] * dBs[seg * 4 + i];
    zp[k][seg] = s;
  }
  __syncthreads();
  if (tid <= KE) {
    float s = 0.f;
#pragma unroll
    for (int seg = 0; seg < 16; ++seg) s += zp[tid][seg];
    zs[tid] = s;
  }
  __syncthreads();
  if (tid < 64) {
    const float rdt = (float)tid * dt;
    float c = 1.f, acc = zs[0];
#pragma unroll
    for (int k = 1; k <= KE; ++k) { c *= rdt / (float)k; acc += c * zs[k]; }
    kloc[d * 64 + tid] = acc;
  }
  if (tid == 0) dts[d] = dt;
}

// Transpose x[b][t][d] -> xT[d][b][t]. 64x64 LDS tiles.
__global__ __launch_bounds__(256) void s4_xt(const float* __restrict__ x,
                                             float* __restrict__ xT) {
  __shared__ float tile[64][65];
  const int t0 = blockIdx.x * 64, d0 = blockIdx.y * 64, b = blockIdx.z;
  const int lt = threadIdx.x & 63, rq = threadIdx.x >> 6;
#pragma unroll
  for (int i = 0; i < 16; ++i) {
    const int row = rq + i * 4;
    tile[row][lt] = x[((size_t)b * Lz + t0 + row) * Dz + d0 + lt];
  }
  __syncthreads();
#pragma unroll
  for (int i = 0; i < 16; ++i) {
    const int row = rq + i * 4;
    xT[((size_t)(d0 + row) * Bz + b) * Lz + t0 + lt] = tile[lt][row];
  }
}

// Chunked state scan, one block per d. Rebuilds E64 row (from Apow + CT)
// and U rows (from Gk + CT) in the prelude, then 32 sequential chunks.
__global__ __launch_bounds__(256) void s4_scan2(
    const float* __restrict__ xT, const float* __restrict__ Apow,
    const float* __restrict__ Gk, const float* __restrict__ dts,
    float* __restrict__ S) {
  __shared__ float As[Nz * SA];
  __shared__ float Gs[(KE + 1) * Nz];
  __shared__ float CT[KE + 1][66];
  __shared__ float Xs[8][64];
  __shared__ float Ss[8][64];
  const int d = blockIdx.x;
  const int tid = threadIdx.x, n = tid & 63, q = tid >> 6;
  const float dt = dts[d];
  if (tid < 65) {
    const float rdt = (float)tid * dt;
    float c = 1.f;
    CT[0][tid] = 1.f;
#pragma unroll
    for (int k = 1; k <= KE; ++k) { c *= rdt / (float)k; CT[k][tid] = c; }
  }
  for (int idx = tid; idx < (KE + 1) * 64; idx += 256)
    Gs[idx] = Gk[(size_t)d * ((KE + 1) * 64) + idx];
  __syncthreads();
  float arowE[64];
#pragma unroll
  for (int m = 0; m < 64; ++m) arowE[m] = 0.f;
#pragma unroll 1
  for (int k = 1; k <= KE; ++k) {
#pragma unroll
    for (int i = 0; i < 4; ++i) {
      const int e = (tid + 256 * i) * 4;
      const int r = e >> 6, c = e & 63;
      const float4 v = *(const float4*)(Apow + (size_t)(k - 1) * 4096 + e);
      As[r * SA + c] = v.x; As[r * SA + c + 1] = v.y;
      As[r * SA + c + 2] = v.z; As[r * SA + c + 3] = v.w;
    }
    __syncthreads();
    const float ce = CT[k][64];   // (64 dt)^k / k!
#pragma unroll
    for (int m = 0; m < 64; ++m) arowE[m] = fmaf(ce, As[n * SA + m], arowE[m]);
    __syncthreads();
  }
  arowE[n] += 1.f;                // identity term: E64[n][n]
  float arowU[64];
#pragma unroll
  for (int j = 0; j < 64; ++j) {
    float u = 0.f;
#pragma unroll
    for (int k = 0; k <= KE; ++k) u = fmaf(CT[k][63 - j], Gs[k * 64 + n], u);
    arowU[j] = u;                 // = (E^{63-j} dB)[n]
  }
  Ss[q][n] = 0.f;
  Ss[q + 4][n] = 0.f;
  __syncthreads();
  const float* xd = xT + (size_t)d * Bz * Lz;
  float* Sd = S + (size_t)d * (32 * 8 * 64);
#pragma unroll 1
  for (int c = 0; c < 32; ++c) {
    Xs[q][n]     = xd[(size_t)q * Lz + c * 64 + n];
    Xs[q + 4][n] = xd[(size_t)(q + 4) * Lz + c * 64 + n];
    Sd[c * 512 + q * 64 + n]       = Ss[q][n];
    Sd[c * 512 + (q + 4) * 64 + n] = Ss[q + 4][n];
    __syncthreads();
    float acc0 = 0.f, acc1 = 0.f;
#pragma unroll
    for (int m = 0; m < 64; m += 4) {
      const float4 s0 = *(const float4*)&Ss[q][m];
      const float4 s1 = *(const float4*)&Ss[q + 4][m];
      const float4 x0 = *(const float4*)&Xs[q][m];
      const float4 x1 = *(const float4*)&Xs[q + 4][m];
      acc0 = fmaf(arowE[m], s0.x, acc0);     acc1 = fmaf(arowE[m], s1.x, acc1);
      acc0 = fmaf(arowE[m + 1], s0.y, acc0); acc1 = fmaf(arowE[m + 1], s1.y, acc1);
      acc0 = fmaf(arowE[m + 2], s0.z, acc0); acc1 = fmaf(arowE[m + 2], s1.z, acc1);
      acc0 = fmaf(arowE[m + 3], s0.w, acc0); acc1 = fmaf(arowE[m + 3], s1.w, acc1);
      acc0 = fmaf(arowU[m], x0.x, acc0);     acc1 = fmaf(arowU[m], x1.x, acc1);
      acc0 = fmaf(arowU[m + 1], x0.y, acc0); acc1 = fmaf(arowU[m + 1], x1.y, acc1);
      acc0 = fmaf(arowU[m + 2], x0.z, acc0); acc1 = fmaf(arowU[m + 2], x1.z, acc1);
      acc0 = fmaf(arowU[m + 3], x0.w, acc0); acc1 = fmaf(arowU[m + 3], x1.w, acc1);
    }
    __syncthreads();
    Ss[q][n] = acc0;
    Ss[q + 4][n] = acc1;
    __syncthreads();
  }
}

// Output: yT[d][b][c*64+r] = W[r] . S[d][c][b] + sum_{j<=r} k[r-j] x[d][b][c*64+j]
// W rows rebuilt from Qk + CT in the prelude.
__global__ __launch_bounds__(256) void s4_out2(
    const float* __restrict__ xT, const float* __restrict__ S,
    const float* __restrict__ Qk, const float* __restrict__ kloc,
    const float* __restrict__ dts, float* __restrict__ yT) {
  __shared__ float Qs[(KE + 1) * Nz];
  __shared__ float CT[KE + 1][66];
  __shared__ float kx[128];
  __shared__ float colS[4][64];
  __shared__ float colX[4][64];
  const int d = blockIdx.x;
  const int tid = threadIdx.x, r = tid & 63, q = tid >> 6;
  const float dt = dts[d];
  if (tid < 65) {
    const float rdt = (float)tid * dt;
    float c = 1.f;
    CT[0][tid] = 1.f;
#pragma unroll
    for (int k = 1; k <= KE; ++k) { c *= rdt / (float)k; CT[k][tid] = c; }
  }
  for (int idx = tid; idx < (KE + 1) * 64; idx += 256)
    Qs[idx] = Qk[(size_t)d * ((KE + 1) * 64) + idx];
  if (tid < 63) kx[tid] = 0.f;
  if (tid < 64) kx[63 + tid] = kloc[d * 64 + tid];
  __syncthreads();
  float arowW[64];
#pragma unroll
  for (int m = 0; m < 64; ++m) {
    float w = 0.f;
#pragma unroll
    for (int k = 0; k <= KE; ++k) w = fmaf(CT[k][r + 1], Qs[k * 64 + m], w);
    arowW[m] = w;                 // = W[r][m] = (C^T E^{r+1})[m]
  }
  const float* xd = xT + (size_t)d * Bz * Lz;
  const float* Sd = S + (size_t)d * (32 * 8 * 64);
  float* yd = yT + (size_t)d * Bz * Lz;
#pragma unroll 1
  for (int p = 0; p < 64; ++p) {
    {
      const int col = p * 4 + q;               // col = c*8 + b
      const int cc = col >> 3, bb = col & 7;
      colS[q][r] = Sd[cc * 512 + bb * 64 + r];
      colX[q][r] = xd[(size_t)bb * Lz + cc * 64 + r];
    }
    __syncthreads();
    const int col = p * 4 + q;
    const int cc = col >> 3, bb = col & 7;
    float acc = 0.f;
#pragma unroll
    for (int m = 0; m < 64; m += 4) {
      const float4 sv = *(const float4*)&colS[q][m];
      acc = fmaf(arowW[m], sv.x, acc);
      acc = fmaf(arowW[m + 1], sv.y, acc);
      acc = fmaf(arowW[m + 2], sv.z, acc);
      acc = fmaf(arowW[m + 3], sv.w, acc);
    }
#pragma unroll
    for (int j = 0; j < 64; j += 4) {
      const float4 xv = *(const float4*)&colX[q][j];
      acc = fmaf(kx[63 + r - j], xv.x, acc);
      acc = fmaf(kx[62 + r - j], xv.y, acc);
      acc = fmaf(kx[61 + r - j], xv.z, acc);
      acc = fmaf(kx[60 + r - j], xv.w, acc);
    }
    yd[(size_t)bb * Lz + cc * 64 + r] = acc;
    __syncthreads();
  }
}

// out[row,c] = sum_d (yT[d][row] + x[row,d]*skip[d]) * W[c,d] + b[c]
__global__ __launch_bounds__(256) void s4_gemm(
    const float* __restrict__ yT, const float* __restrict__ x,
    const float* __restrict__ skip_D, const float* __restrict__ Wo,
    const float* __restrict__ bo, float* __restrict__ out) {
  __shared__ alignas(16) float Ys[64 * 17];
  __shared__ alignas(16) float Ws[64 * 17];
  const int tid = threadIdx.x;
  const int r0 = blockIdx.x * 64;
  const int c0 = blockIdx.y * 64;
  const int brow = r0 >> 11;
  const int t0 = r0 & 2047;
  const int tr = tid >> 4, tc = tid & 15;
  const int lr = tid >> 2, lq = tid & 3;
  float acc[16];
#pragma unroll
  for (int i = 0; i < 16; ++i) acc[i] = 0.f;
  for (int kc = 0; kc < 16; ++kc) {
    const int dc0 = kc * 16;
    const float4 xa = *(const float4*)(x + (size_t)(r0 + lr) * Dz + dc0 + lq * 4);
    const float4 sk = *(const float4*)(skip_D + dc0 + lq * 4);
    const float4 wa = *(const float4*)(Wo + (size_t)(c0 + lr) * Dz + dc0 + lq * 4);
    float yv[4];
#pragma unroll
    for (int i = 0; i < 4; ++i) {
      const int dd = dc0 + lq * 4 + i;
      yv[i] = yT[((size_t)dd * Bz + brow) * Lz + t0 + lr];
    }
    Ys[lr * 17 + lq * 4 + 0] = yv[0] + xa.x * sk.x;
    Ys[lr * 17 + lq * 4 + 1] = yv[1] + xa.y * sk.y;
    Ys[lr * 17 + lq * 4 + 2] = yv[2] + xa.z * sk.z;
    Ys[lr * 17 + lq * 4 + 3] = yv[3] + xa.w * sk.w;
    Ws[lr * 17 + lq * 4 + 0] = wa.x; Ws[lr * 17 + lq * 4 + 1] = wa.y;
    Ws[lr * 17 + lq * 4 + 2] = wa.z; Ws[lr * 17 + lq * 4 + 3] = wa.w;
    __syncthreads();
#pragma unroll
    for (int dk = 0; dk < 16; ++dk) {
      float yvv[4], wv[4];
#pragma unroll
      for (int i = 0; i < 4; ++i) yvv[i] = Ys[(tr * 4 + i) * 17 + dk];
#pragma unroll
      for (int i = 0; i < 4; ++i) wv[i] = Ws[(tc * 4 + i) * 17 + dk];
#pragma unroll
      for (int i = 0; i < 4; ++i)
#pragma unroll
        for (int jj = 0; jj < 4; ++jj)
          acc[i * 4 + jj] = fmaf(yvv[i], wv[jj], acc[i * 4 + jj]);
    }
    __syncthreads();
  }
#pragma unroll
  for (int i = 0; i < 4; ++i)
#pragma unroll
    for (int jj = 0; jj < 4; ++jj) {
      const int cc = c0 + tc * 4 + jj;
      out[(size_t)(r0 + tr * 4 + i) * Dz + cc] = acc[i * 4 + jj] + bo[cc];
    }
}

extern "C" void kernel_launch(void* const* d_in, const int* in_sizes, int n_in,
                              void* d_out, int out_size, void* d_ws, size_t ws_size,
                              hipStream_t stream) {
  const float* x         = (const float*)d_in[0];
  const float* log_A     = (const float*)d_in[1];
  const float* Bp        = (const float*)d_in[2];
  const float* Cp        = (const float*)d_in[3];
  const float* log_delta = (const float*)d_in[4];
  const float* skip_D    = (const float*)d_in[5];
  const float* W_out     = (const float*)d_in[6];
  const float* b_out     = (const float*)d_in[7];
  float* out = (float*)d_out;

  // workspace (floats): xT, yT, S (3 x 4.19M), Apow[8x4096], Gk/Qk[256x576],
  // kloc[256x64], dts[256]  (~51 MB)
  float* xT   = (float*)d_ws;
  float* yT   = xT + (size_t)Dz * Bz * Lz;
  float* S    = yT + (size_t)Dz * Bz * Lz;
  float* Apow = S + (size_t)Dz * (32 * 8 * 64);
  float* Gk   = Apow + (size_t)8 * 4096;
  float* Qk   = Gk + (size_t)Dz * (KE + 1) * 64;
  float* kloc = Qk + (size_t)Dz * (KE + 1) * 64;
  float* dts  = kloc + (size_t)Dz * 64;

  hipLaunchKernelGGL(s4_xt, dim3(Lz / 64, Dz / 64, Bz), dim3(256), 0, stream,
                     x, xT);
  hipLaunchKernelGGL(s4_powinit, dim3(16), dim3(256), 0, stream, log_A, Apow);
  hipLaunchKernelGGL(s4_powmm, dim3(1), dim3(256), 0, stream, Apow, Apow, 0, 1);
  hipLaunchKernelGGL(s4_powmm, dim3(2), dim3(256), 0, stream, Apow, Apow, 1, 2);
  hipLaunchKernelGGL(s4_powmm, dim3(4), dim3(256), 0, stream, Apow, Apow, 3, 4);
  hipLaunchKernelGGL(s4_build2, dim3(Dz), dim3(256), 0, stream,
                     Apow, Bp, Cp, log_delta, Gk, Qk, kloc, dts);
  hipLaunchKernelGGL(s4_scan2, dim3(Dz), dim3(256), 0, stream,
                     xT, Apow, Gk, dts, S);
  hipLaunchKernelGGL(s4_out2, dim3(Dz), dim3(256), 0, stream,
                     xT, S, Qk, kloc, dts, yT);
  hipLaunchKernelGGL(s4_gemm, dim3((Bz * Lz) / 64, Dz / 64), dim3(256), 0, stream,
                     yT, x, skip_D, W_out, b_out, out);
}

// Round 7
// 367.736 us; speedup vs baseline: 1.0015x; 1.0015x over previous
//
#include <hip/hip_runtime.h>

#define Bz 8
#define Lz 2048
#define Dz 256
#define Nz 64
#define SP 68   // b128-aligned LDS stride (powmm)
#define SA 65   // scalar-access LDS stride (conflict-free rows+cols)
#define KE 8    // Taylor order for E^r / E64 / W (norm(64*dt*A) ~ 0.08)
#define KP 11   // p-chain depth = KE + 3 (dB phi1 terms)

__device__ __forceinline__ float softplusf(float x) {
  return (x > 20.f) ? x : log1pf(expf(x));
}

// ---- power-basis kernels: Apow[k-1] = A^k (row-major 64x64), k=1..8 ----

__global__ __launch_bounds__(256) void s4_powinit(const float* __restrict__ log_A,
                                                  float* __restrict__ Apow) {
  const int i = blockIdx.x * 256 + threadIdx.x;
  Apow[i] = softplusf(log_A[i]);
}

// O(blockIdx) = Apow[li] * Apow[blockIdx]; writes Apow[oi + blockIdx].
__global__ __launch_bounds__(256, 1) void s4_powmm(const float* __restrict__ Apow_c,
                                                   float* __restrict__ Apow,
                                                   int li, int oi) {
  __shared__ alignas(16) float LA[Nz * SP];
  __shared__ alignas(16) float LB[Nz * SP];
  const int tid = threadIdx.x;
  const float* L = Apow_c + (size_t)li * 4096;
  const float* R = Apow_c + (size_t)blockIdx.x * 4096;
  float* O = Apow + (size_t)(oi + blockIdx.x) * 4096;
#pragma unroll
  for (int i = 0; i < 4; ++i) {
    const int e = (tid + 256 * i) * 4;
    const int r = e >> 6, c = e & 63;
    *(float4*)&LA[r * SP + c] = *(const float4*)(L + e);
    *(float4*)&LB[r * SP + c] = *(const float4*)(R + e);
  }
  __syncthreads();
  const int n = tid & 63, q = tid >> 6;
  float arow[64];
#pragma unroll
  for (int mm = 0; mm < 16; ++mm) {
    const float4 a4 = *(const float4*)(LA + n * SP + mm * 4);
    arow[4 * mm + 0] = a4.x; arow[4 * mm + 1] = a4.y;
    arow[4 * mm + 2] = a4.z; arow[4 * mm + 3] = a4.w;
  }
  float acc[16];
#pragma unroll
  for (int i = 0; i < 16; ++i) acc[i] = 0.f;
#pragma unroll 8
  for (int m = 0; m < 64; ++m) {
    const float4 b0 = *(const float4*)(LB + m * SP + q * 16 + 0);
    const float4 b1 = *(const float4*)(LB + m * SP + q * 16 + 4);
    const float4 b2 = *(const float4*)(LB + m * SP + q * 16 + 8);
    const float4 b3 = *(const float4*)(LB + m * SP + q * 16 + 12);
    const float a = arow[m];
    acc[0]  = fmaf(a, b0.x, acc[0]);  acc[1]  = fmaf(a, b0.y, acc[1]);
    acc[2]  = fmaf(a, b0.z, acc[2]);  acc[3]  = fmaf(a, b0.w, acc[3]);
    acc[4]  = fmaf(a, b1.x, acc[4]);  acc[5]  = fmaf(a, b1.y, acc[5]);
    acc[6]  = fmaf(a, b1.z, acc[6]);  acc[7]  = fmaf(a, b1.w, acc[7]);
    acc[8]  = fmaf(a, b2.x, acc[8]);  acc[9]  = fmaf(a, b2.y, acc[9]);
    acc[10] = fmaf(a, b2.z, acc[10]); acc[11] = fmaf(a, b2.w, acc[11]);
    acc[12] = fmaf(a, b3.x, acc[12]); acc[13] = fmaf(a, b3.y, acc[13]);
    acc[14] = fmaf(a, b3.z, acc[14]); acc[15] = fmaf(a, b3.w, acc[15]);
  }
#pragma unroll
  for (int v = 0; v < 4; ++v) {
    float4 o;
    o.x = acc[4 * v + 0]; o.y = acc[4 * v + 1];
    o.z = acc[4 * v + 2]; o.w = acc[4 * v + 3];
    *(float4*)(O + n * 64 + q * 16 + 4 * v) = o;
  }
}

// ---- per-d build: chained matvecs on shared A, emit small vectors ----
__global__ __launch_bounds__(256, 1) void s4_build2(
    const float* __restrict__ Apow, const float* __restrict__ Bp,
    const float* __restrict__ Cp, const float* __restrict__ log_delta,
    float* __restrict__ Gk, float* __restrict__ Qk,
    float* __restrict__ kloc, float* __restrict__ dts) {
  __shared__ float As[Nz * SA];
  __shared__ float Pst[KP + 1][Nz];
  __shared__ float Qst[KE + 1][Nz];
  __shared__ float Pv[Nz], Qv[Nz], dBs[Nz];
  __shared__ float prA[4][Nz + 8], prB[4][Nz + 8];
  __shared__ float zp[KE + 1][17], zs[KE + 1];
  const int tid = threadIdx.x;
  const int d = blockIdx.x;
  const int n = tid & 63, qq = tid >> 6;
  const float dt = softplusf(log_delta[d]) + 1e-6f;

#pragma unroll
  for (int i = 0; i < 4; ++i) {
    const int e = (tid + 256 * i) * 4;
    const int r = e >> 6, c = e & 63;
    const float4 v = *(const float4*)(Apow + e);
    As[r * SA + c] = v.x; As[r * SA + c + 1] = v.y;
    As[r * SA + c + 2] = v.z; As[r * SA + c + 3] = v.w;
  }
  if (tid < 64) {
    const float bv = Bp[d * Nz + tid], cv = Cp[d * Nz + tid];
    Pv[tid] = bv; Pst[0][tid] = bv;
    Qv[tid] = cv; Qst[0][tid] = cv;
  }
  __syncthreads();
#pragma unroll 1
  for (int k = 1; k <= KP; ++k) {
    float pp = 0.f, pq = 0.f;
#pragma unroll
    for (int mm = 0; mm < 16; ++mm) {
      const int m = qq * 16 + mm;
      pp += As[n * SA + m] * Pv[m];   // (A p)[n]
      pq += As[m * SA + n] * Qv[m];   // (A^T q)[n]
    }
    prA[qq][n] = pp; prB[qq][n] = pq;
    __syncthreads();
    if (tid < 64) {
      const float np = prA[0][tid] + prA[1][tid] + prA[2][tid] + prA[3][tid];
      Pv[tid] = np; Pst[k][tid] = np;
      if (k <= KE) {
        const float nq = prB[0][tid] + prB[1][tid] + prB[2][tid] + prB[3][tid];
        Qv[tid] = nq; Qst[k][tid] = nq;
      }
    }
    __syncthreads();
  }
  const float dtc0 = dt;
  const float dtc1 = dt * dt * 0.5f;
  const float dtc2 = dtc1 * dt * (1.f / 3.f);
  const float dtc3 = dtc2 * dt * 0.25f;
  if (tid < 64) {
    dBs[tid] = dtc0 * Pst[0][tid] + dtc1 * Pst[1][tid] +
               dtc2 * Pst[2][tid] + dtc3 * Pst[3][tid];
#pragma unroll
    for (int k = 0; k <= KE; ++k) {
      Gk[(size_t)d * ((KE + 1) * 64) + k * 64 + tid] =
          dtc0 * Pst[k][tid] + dtc1 * Pst[k + 1][tid] +
          dtc2 * Pst[k + 2][tid] + dtc3 * Pst[k + 3][tid];
      Qk[(size_t)d * ((KE + 1) * 64) + k * 64 + tid] = Qst[k][tid];
    }
  }
  __syncthreads();
  if (tid < (KE + 1) * 16) {
    const int k = tid >> 4, seg = tid & 15;
    float s = 0.f;
#pragma unroll
    for (int i = 0; i < 4; ++i) s += Qst[k][seg * 4 + i] * dBs[seg * 4 + i];
    zp[k][seg] = s;
  }
  __syncthreads();
  if (tid <= KE) {
    float s = 0.f;
#pragma unroll
    for (int seg = 0; seg < 16; ++seg) s += zp[tid][seg];
    zs[tid] = s;
  }
  __syncthreads();
  if (tid < 64) {
    const float rdt = (float)tid * dt;
    float c = 1.f, acc = zs[0];
#pragma unroll
    for (int k = 1; k <= KE; ++k) { c *= rdt / (float)k; acc += c * zs[k]; }
    kloc[d * 64 + tid] = acc;
  }
  if (tid == 0) dts[d] = dt;
}

// Transpose x[b][t][d] -> xT[d][b][t]. 64x64 LDS tiles.
__global__ __launch_bounds__(256) void s4_xt(const float* __restrict__ x,
                                             float* __restrict__ xT) {
  __shared__ float tile[64][65];
  const int t0 = blockIdx.x * 64, d0 = blockIdx.y * 64, b = blockIdx.z;
  const int lt = threadIdx.x & 63, rq = threadIdx.x >> 6;
#pragma unroll
  for (int i = 0; i < 16; ++i) {
    const int row = rq + i * 4;
    tile[row][lt] = x[((size_t)b * Lz + t0 + row) * Dz + d0 + lt];
  }
  __syncthreads();
#pragma unroll
  for (int i = 0; i < 16; ++i) {
    const int row = rq + i * 4;
    xT[((size_t)(d0 + row) * Bz + b) * Lz + t0 + lt] = tile[lt][row];
  }
}

// Chunked state scan, one block per d (grid = 1 block/CU -> launch_bounds
// (256,1): full VGPR budget, arowE/arowU MUST stay in registers).
__global__ __launch_bounds__(256, 1) void s4_scan2(
    const float* __restrict__ xT, const float* __restrict__ Apow,
    const float* __restrict__ Gk, const float* __restrict__ dts,
    float* __restrict__ S) {
  __shared__ float As[Nz * SA];
  __shared__ float Gs[(KE + 1) * Nz];
  __shared__ float CT[KE + 1][66];
  __shared__ float Xs[8][64];
  __shared__ float Ss[8][64];
  const int d = blockIdx.x;
  const int tid = threadIdx.x, n = tid & 63, q = tid >> 6;
  const float dt = dts[d];
  if (tid < 65) {
    const float rdt = (float)tid * dt;
    float c = 1.f;
    CT[0][tid] = 1.f;
#pragma unroll
    for (int k = 1; k <= KE; ++k) { c *= rdt / (float)k; CT[k][tid] = c; }
  }
  for (int idx = tid; idx < (KE + 1) * 64; idx += 256)
    Gs[idx] = Gk[(size_t)d * ((KE + 1) * 64) + idx];
  __syncthreads();
  float arowE[64];
#pragma unroll
  for (int m = 0; m < 64; ++m) arowE[m] = 0.f;
#pragma unroll 1
  for (int k = 1; k <= KE; ++k) {
#pragma unroll
    for (int i = 0; i < 4; ++i) {
      const int e = (tid + 256 * i) * 4;
      const int r = e >> 6, c = e & 63;
      const float4 v = *(const float4*)(Apow + (size_t)(k - 1) * 4096 + e);
      As[r * SA + c] = v.x; As[r * SA + c + 1] = v.y;
      As[r * SA + c + 2] = v.z; As[r * SA + c + 3] = v.w;
    }
    __syncthreads();
    const float ce = CT[k][64];   // (64 dt)^k / k!
#pragma unroll
    for (int m = 0; m < 64; ++m) arowE[m] = fmaf(ce, As[n * SA + m], arowE[m]);
    __syncthreads();
  }
  arowE[n] += 1.f;                // identity term: E64[n][n]
  float arowU[64];
#pragma unroll
  for (int j = 0; j < 64; ++j) {
    float u = 0.f;
#pragma unroll
    for (int k = 0; k <= KE; ++k) u = fmaf(CT[k][63 - j], Gs[k * 64 + n], u);
    arowU[j] = u;                 // = (E^{63-j} dB)[n]
  }
  Ss[q][n] = 0.f;
  Ss[q + 4][n] = 0.f;
  __syncthreads();
  const float* xd = xT + (size_t)d * Bz * Lz;
  float* Sd = S + (size_t)d * (32 * 8 * 64);
#pragma unroll 1
  for (int c = 0; c < 32; ++c) {
    Xs[q][n]     = xd[(size_t)q * Lz + c * 64 + n];
    Xs[q + 4][n] = xd[(size_t)(q + 4) * Lz + c * 64 + n];
    Sd[c * 512 + q * 64 + n]       = Ss[q][n];
    Sd[c * 512 + (q + 4) * 64 + n] = Ss[q + 4][n];
    __syncthreads();
    float acc0 = 0.f, acc1 = 0.f;
#pragma unroll
    for (int m = 0; m < 64; m += 4) {
      const float4 s0 = *(const float4*)&Ss[q][m];
      const float4 s1 = *(const float4*)&Ss[q + 4][m];
      const float4 x0 = *(const float4*)&Xs[q][m];
      const float4 x1 = *(const float4*)&Xs[q + 4][m];
      acc0 = fmaf(arowE[m], s0.x, acc0);     acc1 = fmaf(arowE[m], s1.x, acc1);
      acc0 = fmaf(arowE[m + 1], s0.y, acc0); acc1 = fmaf(arowE[m + 1], s1.y, acc1);
      acc0 = fmaf(arowE[m + 2], s0.z, acc0); acc1 = fmaf(arowE[m + 2], s1.z, acc1);
      acc0 = fmaf(arowE[m + 3], s0.w, acc0); acc1 = fmaf(arowE[m + 3], s1.w, acc1);
      acc0 = fmaf(arowU[m], x0.x, acc0);     acc1 = fmaf(arowU[m], x1.x, acc1);
      acc0 = fmaf(arowU[m + 1], x0.y, acc0); acc1 = fmaf(arowU[m + 1], x1.y, acc1);
      acc0 = fmaf(arowU[m + 2], x0.z, acc0); acc1 = fmaf(arowU[m + 2], x1.z, acc1);
      acc0 = fmaf(arowU[m + 3], x0.w, acc0); acc1 = fmaf(arowU[m + 3], x1.w, acc1);
    }
    __syncthreads();
    Ss[q][n] = acc0;
    Ss[q + 4][n] = acc1;
    __syncthreads();
  }
}

// Output: yT[d][b][c*64+r] = W[r] . S[d][c][b] + sum_{j<=r} k[r-j] x[d][b][c*64+j]
__global__ __launch_bounds__(256, 1) void s4_out2(
    const float* __restrict__ xT, const float* __restrict__ S,
    const float* __restrict__ Qk, const float* __restrict__ kloc,
    const float* __restrict__ dts, float* __restrict__ yT) {
  __shared__ float Qs[(KE + 1) * Nz];
  __shared__ float CT[KE + 1][66];
  __shared__ float kx[128];
  __shared__ float colS[4][64];
  __shared__ float colX[4][64];
  const int d = blockIdx.x;
  const int tid = threadIdx.x, r = tid & 63, q = tid >> 6;
  const float dt = dts[d];
  if (tid < 65) {
    const float rdt = (float)tid * dt;
    float c = 1.f;
    CT[0][tid] = 1.f;
#pragma unroll
    for (int k = 1; k <= KE; ++k) { c *= rdt / (float)k; CT[k][tid] = c; }
  }
  for (int idx = tid; idx < (KE + 1) * 64; idx += 256)
    Qs[idx] = Qk[(size_t)d * ((KE + 1) * 64) + idx];
  if (tid < 63) kx[tid] = 0.f;
  if (tid < 64) kx[63 + tid] = kloc[d * 64 + tid];
  __syncthreads();
  float arowW[64];
#pragma unroll
  for (int m = 0; m < 64; ++m) {
    float w = 0.f;
#pragma unroll
    for (int k = 0; k <= KE; ++k) w = fmaf(CT[k][r + 1], Qs[k * 64 + m], w);
    arowW[m] = w;                 // = W[r][m] = (C^T E^{r+1})[m]
  }
  const float* xd = xT + (size_t)d * Bz * Lz;
  const float* Sd = S + (size_t)d * (32 * 8 * 64);
  float* yd = yT + (size_t)d * Bz * Lz;
#pragma unroll 1
  for (int p = 0; p < 64; ++p) {
    {
      const int col = p * 4 + q;               // col = c*8 + b
      const int cc = col >> 3, bb = col & 7;
      colS[q][r] = Sd[cc * 512 + bb * 64 + r];
      colX[q][r] = xd[(size_t)bb * Lz + cc * 64 + r];
    }
    __syncthreads();
    const int col = p * 4 + q;
    const int cc = col >> 3, bb = col & 7;
    float acc = 0.f;
#pragma unroll
    for (int m = 0; m < 64; m += 4) {
      const float4 sv = *(const float4*)&colS[q][m];
      acc = fmaf(arowW[m], sv.x, acc);
      acc = fmaf(arowW[m + 1], sv.y, acc);
      acc = fmaf(arowW[m + 2], sv.z, acc);
      acc = fmaf(arowW[m + 3], sv.w, acc);
    }
#pragma unroll
    for (int j = 0; j < 64; j += 4) {
      const float4 xv = *(const float4*)&colX[q][j];
      acc = fmaf(kx[63 + r - j], xv.x, acc);
      acc = fmaf(kx[62 + r - j], xv.y, acc);
      acc = fmaf(kx[61 + r - j], xv.z, acc);
      acc = fmaf(kx[60 + r - j], xv.w, acc);
    }
    yd[(size_t)bb * Lz + cc * 64 + r] = acc;
    __syncthreads();
  }
}

// out[row,c] = sum_d (yT[d][row] + x[row,d]*skip[d]) * W[c,d] + b[c]
__global__ __launch_bounds__(256) void s4_gemm(
    const float* __restrict__ yT, const float* __restrict__ x,
    const float* __restrict__ skip_D, const float* __restrict__ Wo,
    const float* __restrict__ bo, float* __restrict__ out) {
  __shared__ alignas(16) float Ys[64 * 17];
  __shared__ alignas(16) float Ws[64 * 17];
  const int tid = threadIdx.x;
  const int r0 = blockIdx.x * 64;
  const int c0 = blockIdx.y * 64;
  const int brow = r0 >> 11;
  const int t0 = r0 & 2047;
  const int tr = tid >> 4, tc = tid & 15;
  const int lr = tid >> 2, lq = tid & 3;
  float acc[16];
#pragma unroll
  for (int i = 0; i < 16; ++i) acc[i] = 0.f;
  for (int kc = 0; kc < 16; ++kc) {
    const int dc0 = kc * 16;
    const float4 xa = *(const float4*)(x + (size_t)(r0 + lr) * Dz + dc0 + lq * 4);
    const float4 sk = *(const float4*)(skip_D + dc0 + lq * 4);
    const float4 wa = *(const float4*)(Wo + (size_t)(c0 + lr) * Dz + dc0 + lq * 4);
    float yv[4];
#pragma unroll
    for (int i = 0; i < 4; ++i) {
      const int dd = dc0 + lq * 4 + i;
      yv[i] = yT[((size_t)dd * Bz + brow) * Lz + t0 + lr];
    }
    Ys[lr * 17 + lq * 4 + 0] = yv[0] + xa.x * sk.x;
    Ys[lr * 17 + lq * 4 + 1] = yv[1] + xa.y * sk.y;
    Ys[lr * 17 + lq * 4 + 2] = yv[2] + xa.z * sk.z;
    Ys[lr * 17 + lq * 4 + 3] = yv[3] + xa.w * sk.w;
    Ws[lr * 17 + lq * 4 + 0] = wa.x; Ws[lr * 17 + lq * 4 + 1] = wa.y;
    Ws[lr * 17 + lq * 4 + 2] = wa.z; Ws[lr * 17 + lq * 4 + 3] = wa.w;
    __syncthreads();
#pragma unroll
    for (int dk = 0; dk < 16; ++dk) {
      float yvv[4], wv[4];
#pragma unroll
      for (int i = 0; i < 4; ++i) yvv[i] = Ys[(tr * 4 + i) * 17 + dk];
#pragma unroll
      for (int i = 0; i < 4; ++i) wv[i] = Ws[(tc * 4 + i) * 17 + dk];
#pragma unroll
      for (int i = 0; i < 4; ++i)
#pragma unroll
        for (int jj = 0; jj < 4; ++jj)
          acc[i * 4 + jj] = fmaf(yvv[i], wv[jj], acc[i * 4 + jj]);
    }
    __syncthreads();
  }
#pragma unroll
  for (int i = 0; i < 4; ++i)
#pragma unroll
    for (int jj = 0; jj < 4; ++jj) {
      const int cc = c0 + tc * 4 + jj;
      out[(size_t)(r0 + tr * 4 + i) * Dz + cc] = acc[i * 4 + jj] + bo[cc];
    }
}

extern "C" void kernel_launch(void* const* d_in, const int* in_sizes, int n_in,
                              void* d_out, int out_size, void* d_ws, size_t ws_size,
                              hipStream_t stream) {
  const float* x         = (const float*)d_in[0];
  const float* log_A     = (const float*)d_in[1];
  const float* Bp        = (const float*)d_in[2];
  const float* Cp        = (const float*)d_in[3];
  const float* log_delta = (const float*)d_in[4];
  const float* skip_D    = (const float*)d_in[5];
  const float* W_out     = (const float*)d_in[6];
  const float* b_out     = (const float*)d_in[7];
  float* out = (float*)d_out;

  float* xT   = (float*)d_ws;
  float* yT   = xT + (size_t)Dz * Bz * Lz;
  float* S    = yT + (size_t)Dz * Bz * Lz;
  float* Apow = S + (size_t)Dz * (32 * 8 * 64);
  float* Gk   = Apow + (size_t)8 * 4096;
  float* Qk   = Gk + (size_t)Dz * (KE + 1) * 64;
  float* kloc = Qk + (size_t)Dz * (KE + 1) * 64;
  float* dts  = kloc + (size_t)Dz * 64;

  hipLaunchKernelGGL(s4_xt, dim3(Lz / 64, Dz / 64, Bz), dim3(256), 0, stream,
                     x, xT);
  hipLaunchKernelGGL(s4_powinit, dim3(16), dim3(256), 0, stream, log_A, Apow);
  hipLaunchKernelGGL(s4_powmm, dim3(1), dim3(256), 0, stream, Apow, Apow, 0, 1);
  hipLaunchKernelGGL(s4_powmm, dim3(2), dim3(256), 0, stream, Apow, Apow, 1, 2);
  hipLaunchKernelGGL(s4_powmm, dim3(4), dim3(256), 0, stream, Apow, Apow, 3, 4);
  hipLaunchKernelGGL(s4_build2, dim3(Dz), dim3(256), 0, stream,
                     Apow, Bp, Cp, log_delta, Gk, Qk, kloc, dts);
  hipLaunchKernelGGL(s4_scan2, dim3(Dz), dim3(256), 0, stream,
                     xT, Apow, Gk, dts, S);
  hipLaunchKernelGGL(s4_out2, dim3(Dz), dim3(256), 0, stream,
                     xT, S, Qk, kloc, dts, yT);
  hipLaunchKernelGGL(s4_gemm, dim3((Bz * Lz) / 64, Dz / 64), dim3(256), 0, stream,
                     yT, x, skip_D, W_out, b_out, out);
}

// Round 8
// 297.217 us; speedup vs baseline: 1.2391x; 1.2373x over previous
//
#include <hip/hip_runtime.h>

#define Bz 8
#define Lz 2048
#define Dz 256
#define Nz 64
#define SP 68   // b128-aligned LDS stride (powmm)
#define SA 65   // scalar-access LDS stride (conflict-free rows+cols)
#define KE 8    // Taylor order for E^r / E64 / W (norm(64*dt*A) ~ 0.08)
#define KP 11   // p-chain depth = KE + 3 (dB phi1 terms)

__device__ __forceinline__ float softplusf(float x) {
  return (x > 20.f) ? x : log1pf(expf(x));
}

// ---- power-basis kernels: Apow[k-1] = A^k (row-major 64x64), k=1..8 ----

__global__ __launch_bounds__(256) void s4_powinit(const float* __restrict__ log_A,
                                                  float* __restrict__ Apow) {
  const int i = blockIdx.x * 256 + threadIdx.x;
  Apow[i] = softplusf(log_A[i]);
}

// O(blockIdx) = Apow[li] * Apow[blockIdx]; writes Apow[oi + blockIdx].
__global__ __launch_bounds__(256, 1) void s4_powmm(const float* __restrict__ Apow_c,
                                                   float* __restrict__ Apow,
                                                   int li, int oi) {
  __shared__ alignas(16) float LA[Nz * SP];
  __shared__ alignas(16) float LB[Nz * SP];
  const int tid = threadIdx.x;
  const float* L = Apow_c + (size_t)li * 4096;
  const float* R = Apow_c + (size_t)blockIdx.x * 4096;
  float* O = Apow + (size_t)(oi + blockIdx.x) * 4096;
#pragma unroll
  for (int i = 0; i < 4; ++i) {
    const int e = (tid + 256 * i) * 4;
    const int r = e >> 6, c = e & 63;
    *(float4*)&LA[r * SP + c] = *(const float4*)(L + e);
    *(float4*)&LB[r * SP + c] = *(const float4*)(R + e);
  }
  __syncthreads();
  const int n = tid & 63, q = tid >> 6;
  float arow[64];
#pragma unroll
  for (int mm = 0; mm < 16; ++mm) {
    const float4 a4 = *(const float4*)(LA + n * SP + mm * 4);
    arow[4 * mm + 0] = a4.x; arow[4 * mm + 1] = a4.y;
    arow[4 * mm + 2] = a4.z; arow[4 * mm + 3] = a4.w;
  }
  float acc[16];
#pragma unroll
  for (int i = 0; i < 16; ++i) acc[i] = 0.f;
#pragma unroll 8
  for (int m = 0; m < 64; ++m) {
    const float4 b0 = *(const float4*)(LB + m * SP + q * 16 + 0);
    const float4 b1 = *(const float4*)(LB + m * SP + q * 16 + 4);
    const float4 b2 = *(const float4*)(LB + m * SP + q * 16 + 8);
    const float4 b3 = *(const float4*)(LB + m * SP + q * 16 + 12);
    const float a = arow[m];
    acc[0]  = fmaf(a, b0.x, acc[0]);  acc[1]  = fmaf(a, b0.y, acc[1]);
    acc[2]  = fmaf(a, b0.z, acc[2]);  acc[3]  = fmaf(a, b0.w, acc[3]);
    acc[4]  = fmaf(a, b1.x, acc[4]);  acc[5]  = fmaf(a, b1.y, acc[5]);
    acc[6]  = fmaf(a, b1.z, acc[6]);  acc[7]  = fmaf(a, b1.w, acc[7]);
    acc[8]  = fmaf(a, b2.x, acc[8]);  acc[9]  = fmaf(a, b2.y, acc[9]);
    acc[10] = fmaf(a, b2.z, acc[10]); acc[11] = fmaf(a, b2.w, acc[11]);
    acc[12] = fmaf(a, b3.x, acc[12]); acc[13] = fmaf(a, b3.y, acc[13]);
    acc[14] = fmaf(a, b3.z, acc[14]); acc[15] = fmaf(a, b3.w, acc[15]);
  }
#pragma unroll
  for (int v = 0; v < 4; ++v) {
    float4 o;
    o.x = acc[4 * v + 0]; o.y = acc[4 * v + 1];
    o.z = acc[4 * v + 2]; o.w = acc[4 * v + 3];
    *(float4*)(O + n * 64 + q * 16 + 4 * v) = o;
  }
}

// ---- per-d build: chained matvecs on shared A, emit small vectors ----
__global__ __launch_bounds__(256, 1) void s4_build2(
    const float* __restrict__ Apow, const float* __restrict__ Bp,
    const float* __restrict__ Cp, const float* __restrict__ log_delta,
    float* __restrict__ Gk, float* __restrict__ Qk,
    float* __restrict__ kloc, float* __restrict__ dts) {
  __shared__ float As[Nz * SA];
  __shared__ float Pst[KP + 1][Nz];
  __shared__ float Qst[KE + 1][Nz];
  __shared__ float Pv[Nz], Qv[Nz], dBs[Nz];
  __shared__ float prA[4][Nz + 8], prB[4][Nz + 8];
  __shared__ float zp[KE + 1][17], zs[KE + 1];
  const int tid = threadIdx.x;
  const int d = blockIdx.x;
  const int n = tid & 63, qq = tid >> 6;
  const float dt = softplusf(log_delta[d]) + 1e-6f;

#pragma unroll
  for (int i = 0; i < 4; ++i) {
    const int e = (tid + 256 * i) * 4;
    const int r = e >> 6, c = e & 63;
    const float4 v = *(const float4*)(Apow + e);
    As[r * SA + c] = v.x; As[r * SA + c + 1] = v.y;
    As[r * SA + c + 2] = v.z; As[r * SA + c + 3] = v.w;
  }
  if (tid < 64) {
    const float bv = Bp[d * Nz + tid], cv = Cp[d * Nz + tid];
    Pv[tid] = bv; Pst[0][tid] = bv;
    Qv[tid] = cv; Qst[0][tid] = cv;
  }
  __syncthreads();
#pragma unroll 1
  for (int k = 1; k <= KP; ++k) {
    float pp = 0.f, pq = 0.f;
#pragma unroll
    for (int mm = 0; mm < 16; ++mm) {
      const int m = qq * 16 + mm;
      pp += As[n * SA + m] * Pv[m];   // (A p)[n]
      pq += As[m * SA + n] * Qv[m];   // (A^T q)[n]
    }
    prA[qq][n] = pp; prB[qq][n] = pq;
    __syncthreads();
    if (tid < 64) {
      const float np = prA[0][tid] + prA[1][tid] + prA[2][tid] + prA[3][tid];
      Pv[tid] = np; Pst[k][tid] = np;
      if (k <= KE) {
        const float nq = prB[0][tid] + prB[1][tid] + prB[2][tid] + prB[3][tid];
        Qv[tid] = nq; Qst[k][tid] = nq;
      }
    }
    __syncthreads();
  }
  const float dtc0 = dt;
  const float dtc1 = dt * dt * 0.5f;
  const float dtc2 = dtc1 * dt * (1.f / 3.f);
  const float dtc3 = dtc2 * dt * 0.25f;
  if (tid < 64) {
    dBs[tid] = dtc0 * Pst[0][tid] + dtc1 * Pst[1][tid] +
               dtc2 * Pst[2][tid] + dtc3 * Pst[3][tid];
#pragma unroll
    for (int k = 0; k <= KE; ++k) {
      Gk[(size_t)d * ((KE + 1) * 64) + k * 64 + tid] =
          dtc0 * Pst[k][tid] + dtc1 * Pst[k + 1][tid] +
          dtc2 * Pst[k + 2][tid] + dtc3 * Pst[k + 3][tid];
      Qk[(size_t)d * ((KE + 1) * 64) + k * 64 + tid] = Qst[k][tid];
    }
  }
  __syncthreads();
  if (tid < (KE + 1) * 16) {
    const int k = tid >> 4, seg = tid & 15;
    float s = 0.f;
#pragma unroll
    for (int i = 0; i < 4; ++i) s += Qst[k][seg * 4 + i] * dBs[seg * 4 + i];
    zp[k][seg] = s;
  }
  __syncthreads();
  if (tid <= KE) {
    float s = 0.f;
#pragma unroll
    for (int seg = 0; seg < 16; ++seg) s += zp[tid][seg];
    zs[tid] = s;
  }
  __syncthreads();
  if (tid < 64) {
    const float rdt = (float)tid * dt;
    float c = 1.f, acc = zs[0];
#pragma unroll
    for (int k = 1; k <= KE; ++k) { c *= rdt / (float)k; acc += c * zs[k]; }
    kloc[d * 64 + tid] = acc;
  }
  if (tid == 0) dts[d] = dt;
}

// Transpose x[b][t][d] -> xT[d][b][t]. 64x64 LDS tiles.
__global__ __launch_bounds__(256) void s4_xt(const float* __restrict__ x,
                                             float* __restrict__ xT) {
  __shared__ float tile[64][65];
  const int t0 = blockIdx.x * 64, d0 = blockIdx.y * 64, b = blockIdx.z;
  const int lt = threadIdx.x & 63, rq = threadIdx.x >> 6;
#pragma unroll
  for (int i = 0; i < 16; ++i) {
    const int row = rq + i * 4;
    tile[row][lt] = x[((size_t)b * Lz + t0 + row) * Dz + d0 + lt];
  }
  __syncthreads();
#pragma unroll
  for (int i = 0; i < 16; ++i) {
    const int row = rq + i * 4;
    xT[((size_t)(d0 + row) * Bz + b) * Lz + t0 + lt] = tile[lt][row];
  }
}

// Chunked state scan, one block per d.
// NOTE: arowE/arowU must use ONLY compile-time indices — a single dynamic
// index (the old `arowE[n] += 1.f`) demotes the whole array to scratch
// (r7: VGPR=52, 47 MB scratch traffic). The E64 identity term is applied
// by initializing the accumulator with the thread's own previous state.
__global__ __launch_bounds__(256, 1) void s4_scan2(
    const float* __restrict__ xT, const float* __restrict__ Apow,
    const float* __restrict__ Gk, const float* __restrict__ dts,
    float* __restrict__ S) {
  __shared__ float As[Nz * SA];
  __shared__ float Gs[(KE + 1) * Nz];
  __shared__ float CT[KE + 1][66];
  __shared__ float Xs[8][64];
  __shared__ float Ss[8][64];
  const int d = blockIdx.x;
  const int tid = threadIdx.x, n = tid & 63, q = tid >> 6;
  const float dt = dts[d];
  if (tid < 65) {
    const float rdt = (float)tid * dt;
    float c = 1.f;
    CT[0][tid] = 1.f;
#pragma unroll
    for (int k = 1; k <= KE; ++k) { c *= rdt / (float)k; CT[k][tid] = c; }
  }
  for (int idx = tid; idx < (KE + 1) * 64; idx += 256)
    Gs[idx] = Gk[(size_t)d * ((KE + 1) * 64) + idx];
  __syncthreads();
  float arowE[64];   // arowE[m] = E64[n][m] - I[n][m]  (identity handled below)
#pragma unroll
  for (int m = 0; m < 64; ++m) arowE[m] = 0.f;
#pragma unroll 1
  for (int k = 1; k <= KE; ++k) {
#pragma unroll
    for (int i = 0; i < 4; ++i) {
      const int e = (tid + 256 * i) * 4;
      const int r = e >> 6, c = e & 63;
      const float4 v = *(const float4*)(Apow + (size_t)(k - 1) * 4096 + e);
      As[r * SA + c] = v.x; As[r * SA + c + 1] = v.y;
      As[r * SA + c + 2] = v.z; As[r * SA + c + 3] = v.w;
    }
    __syncthreads();
    const float ce = CT[k][64];   // (64 dt)^k / k!
#pragma unroll
    for (int m = 0; m < 64; ++m) arowE[m] = fmaf(ce, As[n * SA + m], arowE[m]);
    __syncthreads();
  }
  float arowU[64];
#pragma unroll
  for (int j = 0; j < 64; ++j) {
    float u = 0.f;
#pragma unroll
    for (int k = 0; k <= KE; ++k) u = fmaf(CT[k][63 - j], Gs[k * 64 + n], u);
    arowU[j] = u;                 // = (E^{63-j} dB)[n]
  }
  Ss[q][n] = 0.f;
  Ss[q + 4][n] = 0.f;
  __syncthreads();
  const float* xd = xT + (size_t)d * Bz * Lz;
  float* Sd = S + (size_t)d * (32 * 8 * 64);
#pragma unroll 1
  for (int c = 0; c < 32; ++c) {
    Xs[q][n]     = xd[(size_t)q * Lz + c * 64 + n];
    Xs[q + 4][n] = xd[(size_t)(q + 4) * Lz + c * 64 + n];
    Sd[c * 512 + q * 64 + n]       = Ss[q][n];
    Sd[c * 512 + (q + 4) * 64 + n] = Ss[q + 4][n];
    __syncthreads();
    float acc0 = Ss[q][n];        // E64 identity term (uniform LDS read)
    float acc1 = Ss[q + 4][n];
#pragma unroll
    for (int m = 0; m < 64; m += 4) {
      const float4 s0 = *(const float4*)&Ss[q][m];
      const float4 s1 = *(const float4*)&Ss[q + 4][m];
      const float4 x0 = *(const float4*)&Xs[q][m];
      const float4 x1 = *(const float4*)&Xs[q + 4][m];
      acc0 = fmaf(arowE[m], s0.x, acc0);     acc1 = fmaf(arowE[m], s1.x, acc1);
      acc0 = fmaf(arowE[m + 1], s0.y, acc0); acc1 = fmaf(arowE[m + 1], s1.y, acc1);
      acc0 = fmaf(arowE[m + 2], s0.z, acc0); acc1 = fmaf(arowE[m + 2], s1.z, acc1);
      acc0 = fmaf(arowE[m + 3], s0.w, acc0); acc1 = fmaf(arowE[m + 3], s1.w, acc1);
      acc0 = fmaf(arowU[m], x0.x, acc0);     acc1 = fmaf(arowU[m], x1.x, acc1);
      acc0 = fmaf(arowU[m + 1], x0.y, acc0); acc1 = fmaf(arowU[m + 1], x1.y, acc1);
      acc0 = fmaf(arowU[m + 2], x0.z, acc0); acc1 = fmaf(arowU[m + 2], x1.z, acc1);
      acc0 = fmaf(arowU[m + 3], x0.w, acc0); acc1 = fmaf(arowU[m + 3], x1.w, acc1);
    }
    __syncthreads();
    Ss[q][n] = acc0;
    Ss[q + 4][n] = acc1;
    __syncthreads();
  }
}

// Output: yT[d][b][c*64+r] = W[r] . S[d][c][b] + sum_{j<=r} k[r-j] x[d][b][c*64+j]
__global__ __launch_bounds__(256, 1) void s4_out2(
    const float* __restrict__ xT, const float* __restrict__ S,
    const float* __restrict__ Qk, const float* __restrict__ kloc,
    const float* __restrict__ dts, float* __restrict__ yT) {
  __shared__ float Qs[(KE + 1) * Nz];
  __shared__ float CT[KE + 1][66];
  __shared__ float kx[128];
  __shared__ float colS[4][64];
  __shared__ float colX[4][64];
  const int d = blockIdx.x;
  const int tid = threadIdx.x, r = tid & 63, q = tid >> 6;
  const float dt = dts[d];
  if (tid < 65) {
    const float rdt = (float)tid * dt;
    float c = 1.f;
    CT[0][tid] = 1.f;
#pragma unroll
    for (int k = 1; k <= KE; ++k) { c *= rdt / (float)k; CT[k][tid] = c; }
  }
  for (int idx = tid; idx < (KE + 1) * 64; idx += 256)
    Qs[idx] = Qk[(size_t)d * ((KE + 1) * 64) + idx];
  if (tid < 63) kx[tid] = 0.f;
  if (tid < 64) kx[63 + tid] = kloc[d * 64 + tid];
  __syncthreads();
  float arowW[64];
#pragma unroll
  for (int m = 0; m < 64; ++m) {
    float w = 0.f;
#pragma unroll
    for (int k = 0; k <= KE; ++k) w = fmaf(CT[k][r + 1], Qs[k * 64 + m], w);
    arowW[m] = w;                 // = W[r][m] = (C^T E^{r+1})[m]
  }
  const float* xd = xT + (size_t)d * Bz * Lz;
  const float* Sd = S + (size_t)d * (32 * 8 * 64);
  float* yd = yT + (size_t)d * Bz * Lz;
#pragma unroll 1
  for (int p = 0; p < 64; ++p) {
    {
      const int col = p * 4 + q;               // col = c*8 + b
      const int cc = col >> 3, bb = col & 7;
      colS[q][r] = Sd[cc * 512 + bb * 64 + r];
      colX[q][r] = xd[(size_t)bb * Lz + cc * 64 + r];
    }
    __syncthreads();
    const int col = p * 4 + q;
    const int cc = col >> 3, bb = col & 7;
    float acc = 0.f;
#pragma unroll
    for (int m = 0; m < 64; m += 4) {
      const float4 sv = *(const float4*)&colS[q][m];
      acc = fmaf(arowW[m], sv.x, acc);
      acc = fmaf(arowW[m + 1], sv.y, acc);
      acc = fmaf(arowW[m + 2], sv.z, acc);
      acc = fmaf(arowW[m + 3], sv.w, acc);
    }
#pragma unroll
    for (int j = 0; j < 64; j += 4) {
      const float4 xv = *(const float4*)&colX[q][j];
      acc = fmaf(kx[63 + r - j], xv.x, acc);
      acc = fmaf(kx[62 + r - j], xv.y, acc);
      acc = fmaf(kx[61 + r - j], xv.z, acc);
      acc = fmaf(kx[60 + r - j], xv.w, acc);
    }
    yd[(size_t)bb * Lz + cc * 64 + r] = acc;
    __syncthreads();
  }
}

// out[row,c] = sum_d (yT[d][row] + x[row,d]*skip[d]) * W[c,d] + b[c]
__global__ __launch_bounds__(256) void s4_gemm(
    const float* __restrict__ yT, const float* __restrict__ x,
    const float* __restrict__ skip_D, const float* __restrict__ Wo,
    const float* __restrict__ bo, float* __restrict__ out) {
  __shared__ alignas(16) float Ys[64 * 17];
  __shared__ alignas(16) float Ws[64 * 17];
  const int tid = threadIdx.x;
  const int r0 = blockIdx.x * 64;
  const int c0 = blockIdx.y * 64;
  const int brow = r0 >> 11;
  const int t0 = r0 & 2047;
  const int tr = tid >> 4, tc = tid & 15;
  const int lr = tid >> 2, lq = tid & 3;
  float acc[16];
#pragma unroll
  for (int i = 0; i < 16; ++i) acc[i] = 0.f;
  for (int kc = 0; kc < 16; ++kc) {
    const int dc0 = kc * 16;
    const float4 xa = *(const float4*)(x + (size_t)(r0 + lr) * Dz + dc0 + lq * 4);
    const float4 sk = *(const float4*)(skip_D + dc0 + lq * 4);
    const float4 wa = *(const float4*)(Wo + (size_t)(c0 + lr) * Dz + dc0 + lq * 4);
    float yv[4];
#pragma unroll
    for (int i = 0; i < 4; ++i) {
      const int dd = dc0 + lq * 4 + i;
      yv[i] = yT[((size_t)dd * Bz + brow) * Lz + t0 + lr];
    }
    Ys[lr * 17 + lq * 4 + 0] = yv[0] + xa.x * sk.x;
    Ys[lr * 17 + lq * 4 + 1] = yv[1] + xa.y * sk.y;
    Ys[lr * 17 + lq * 4 + 2] = yv[2] + xa.z * sk.z;
    Ys[lr * 17 + lq * 4 + 3] = yv[3] + xa.w * sk.w;
    Ws[lr * 17 + lq * 4 + 0] = wa.x; Ws[lr * 17 + lq * 4 + 1] = wa.y;
    Ws[lr * 17 + lq * 4 + 2] = wa.z; Ws[lr * 17 + lq * 4 + 3] = wa.w;
    __syncthreads();
#pragma unroll
    for (int dk = 0; dk < 16; ++dk) {
      float yvv[4], wv[4];
#pragma unroll
      for (int i = 0; i < 4; ++i) yvv[i] = Ys[(tr * 4 + i) * 17 + dk];
#pragma unroll
      for (int i = 0; i < 4; ++i) wv[i] = Ws[(tc * 4 + i) * 17 + dk];
#pragma unroll
      for (int i = 0; i < 4; ++i)
#pragma unroll
        for (int jj = 0; jj < 4; ++jj)
          acc[i * 4 + jj] = fmaf(yvv[i], wv[jj], acc[i * 4 + jj]);
    }
    __syncthreads();
  }
#pragma unroll
  for (int i = 0; i < 4; ++i)
#pragma unroll
    for (int jj = 0; jj < 4; ++jj) {
      const int cc = c0 + tc * 4 + jj;
      out[(size_t)(r0 + tr * 4 + i) * Dz + cc] = acc[i * 4 + jj] + bo[cc];
    }
}

extern "C" void kernel_launch(void* const* d_in, const int* in_sizes, int n_in,
                              void* d_out, int out_size, void* d_ws, size_t ws_size,
                              hipStream_t stream) {
  const float* x         = (const float*)d_in[0];
  const float* log_A     = (const float*)d_in[1];
  const float* Bp        = (const float*)d_in[2];
  const float* Cp        = (const float*)d_in[3];
  const float* log_delta = (const float*)d_in[4];
  const float* skip_D    = (const float*)d_in[5];
  const float* W_out     = (const float*)d_in[6];
  const float* b_out     = (const float*)d_in[7];
  float* out = (float*)d_out;

  float* xT   = (float*)d_ws;
  float* yT   = xT + (size_t)Dz * Bz * Lz;
  float* S    = yT + (size_t)Dz * Bz * Lz;
  float* Apow = S + (size_t)Dz * (32 * 8 * 64);
  float* Gk   = Apow + (size_t)8 * 4096;
  float* Qk   = Gk + (size_t)Dz * (KE + 1) * 64;
  float* kloc = Qk + (size_t)Dz * (KE + 1) * 64;
  float* dts  = kloc + (size_t)Dz * 64;

  hipLaunchKernelGGL(s4_xt, dim3(Lz / 64, Dz / 64, Bz), dim3(256), 0, stream,
                     x, xT);
  hipLaunchKernelGGL(s4_powinit, dim3(16), dim3(256), 0, stream, log_A, Apow);
  hipLaunchKernelGGL(s4_powmm, dim3(1), dim3(256), 0, stream, Apow, Apow, 0, 1);
  hipLaunchKernelGGL(s4_powmm, dim3(2), dim3(256), 0, stream, Apow, Apow, 1, 2);
  hipLaunchKernelGGL(s4_powmm, dim3(4), dim3(256), 0, stream, Apow, Apow, 3, 4);
  hipLaunchKernelGGL(s4_build2, dim3(Dz), dim3(256), 0, stream,
                     Apow, Bp, Cp, log_delta, Gk, Qk, kloc, dts);
  hipLaunchKernelGGL(s4_scan2, dim3(Dz), dim3(256), 0, stream,
                     xT, Apow, Gk, dts, S);
  hipLaunchKernelGGL(s4_out2, dim3(Dz), dim3(256), 0, stream,
                     xT, S, Qk, kloc, dts, yT);
  hipLaunchKernelGGL(s4_gemm, dim3((Bz * Lz) / 64, Dz / 64), dim3(256), 0, stream,
                     yT, x, skip_D, W_out, b_out, out);
}

// Round 9
// 256.339 us; speedup vs baseline: 1.4367x; 1.1595x over previous
//
#include <hip/hip_runtime.h>

#define Bz 8
#define Lz 2048
#define Dz 256
#define Nz 64
#define SP 68   // b128-aligned LDS stride (powmm)
#define SA 65   // scalar-access LDS stride (conflict-free rows+cols)
#define SM 132  // out3 LDS stride: 16B-aligned, col-spacing-1 reads are 2-way
#define KE 8    // Taylor order for E^r / E64 / W (norm(64*dt*A) ~ 0.08)
#define KP 11   // p-chain depth = KE + 3 (dB phi1 terms)

__device__ __forceinline__ float softplusf(float x) {
  return (x > 20.f) ? x : log1pf(expf(x));
}

// ---- power-basis kernels: Apow[k-1] = A^k (row-major 64x64), k=1..8 ----

__global__ __launch_bounds__(256) void s4_powinit(const float* __restrict__ log_A,
                                                  float* __restrict__ Apow) {
  const int i = blockIdx.x * 256 + threadIdx.x;
  Apow[i] = softplusf(log_A[i]);
}

// O(blockIdx) = Apow[li] * Apow[blockIdx]; writes Apow[oi + blockIdx].
__global__ __launch_bounds__(256, 1) void s4_powmm(const float* __restrict__ Apow_c,
                                                   float* __restrict__ Apow,
                                                   int li, int oi) {
  __shared__ alignas(16) float LA[Nz * SP];
  __shared__ alignas(16) float LB[Nz * SP];
  const int tid = threadIdx.x;
  const float* L = Apow_c + (size_t)li * 4096;
  const float* R = Apow_c + (size_t)blockIdx.x * 4096;
  float* O = Apow + (size_t)(oi + blockIdx.x) * 4096;
#pragma unroll
  for (int i = 0; i < 4; ++i) {
    const int e = (tid + 256 * i) * 4;
    const int r = e >> 6, c = e & 63;
    *(float4*)&LA[r * SP + c] = *(const float4*)(L + e);
    *(float4*)&LB[r * SP + c] = *(const float4*)(R + e);
  }
  __syncthreads();
  const int n = tid & 63, q = tid >> 6;
  float arow[64];
#pragma unroll
  for (int mm = 0; mm < 16; ++mm) {
    const float4 a4 = *(const float4*)(LA + n * SP + mm * 4);
    arow[4 * mm + 0] = a4.x; arow[4 * mm + 1] = a4.y;
    arow[4 * mm + 2] = a4.z; arow[4 * mm + 3] = a4.w;
  }
  float acc[16];
#pragma unroll
  for (int i = 0; i < 16; ++i) acc[i] = 0.f;
#pragma unroll 8
  for (int m = 0; m < 64; ++m) {
    const float4 b0 = *(const float4*)(LB + m * SP + q * 16 + 0);
    const float4 b1 = *(const float4*)(LB + m * SP + q * 16 + 4);
    const float4 b2 = *(const float4*)(LB + m * SP + q * 16 + 8);
    const float4 b3 = *(const float4*)(LB + m * SP + q * 16 + 12);
    const float a = arow[m];
    acc[0]  = fmaf(a, b0.x, acc[0]);  acc[1]  = fmaf(a, b0.y, acc[1]);
    acc[2]  = fmaf(a, b0.z, acc[2]);  acc[3]  = fmaf(a, b0.w, acc[3]);
    acc[4]  = fmaf(a, b1.x, acc[4]);  acc[5]  = fmaf(a, b1.y, acc[5]);
    acc[6]  = fmaf(a, b1.z, acc[6]);  acc[7]  = fmaf(a, b1.w, acc[7]);
    acc[8]  = fmaf(a, b2.x, acc[8]);  acc[9]  = fmaf(a, b2.y, acc[9]);
    acc[10] = fmaf(a, b2.z, acc[10]); acc[11] = fmaf(a, b2.w, acc[11]);
    acc[12] = fmaf(a, b3.x, acc[12]); acc[13] = fmaf(a, b3.y, acc[13]);
    acc[14] = fmaf(a, b3.z, acc[14]); acc[15] = fmaf(a, b3.w, acc[15]);
  }
#pragma unroll
  for (int v = 0; v < 4; ++v) {
    float4 o;
    o.x = acc[4 * v + 0]; o.y = acc[4 * v + 1];
    o.z = acc[4 * v + 2]; o.w = acc[4 * v + 3];
    *(float4*)(O + n * 64 + q * 16 + 4 * v) = o;
  }
}

// ---- per-d build: chained matvecs on shared A, emit small vectors ----
__global__ __launch_bounds__(256, 1) void s4_build2(
    const float* __restrict__ Apow, const float* __restrict__ Bp,
    const float* __restrict__ Cp, const float* __restrict__ log_delta,
    float* __restrict__ Gk, float* __restrict__ Qk,
    float* __restrict__ kloc, float* __restrict__ dts) {
  __shared__ float As[Nz * SA];
  __shared__ float Pst[KP + 1][Nz];
  __shared__ float Qst[KE + 1][Nz];
  __shared__ float Pv[Nz], Qv[Nz], dBs[Nz];
  __shared__ float prA[4][Nz + 8], prB[4][Nz + 8];
  __shared__ float zp[KE + 1][17], zs[KE + 1];
  const int tid = threadIdx.x;
  const int d = blockIdx.x;
  const int n = tid & 63, qq = tid >> 6;
  const float dt = softplusf(log_delta[d]) + 1e-6f;

#pragma unroll
  for (int i = 0; i < 4; ++i) {
    const int e = (tid + 256 * i) * 4;
    const int r = e >> 6, c = e & 63;
    const float4 v = *(const float4*)(Apow + e);
    As[r * SA + c] = v.x; As[r * SA + c + 1] = v.y;
    As[r * SA + c + 2] = v.z; As[r * SA + c + 3] = v.w;
  }
  if (tid < 64) {
    const float bv = Bp[d * Nz + tid], cv = Cp[d * Nz + tid];
    Pv[tid] = bv; Pst[0][tid] = bv;
    Qv[tid] = cv; Qst[0][tid] = cv;
  }
  __syncthreads();
#pragma unroll 1
  for (int k = 1; k <= KP; ++k) {
    float pp = 0.f, pq = 0.f;
#pragma unroll
    for (int mm = 0; mm < 16; ++mm) {
      const int m = qq * 16 + mm;
      pp += As[n * SA + m] * Pv[m];   // (A p)[n]
      pq += As[m * SA + n] * Qv[m];   // (A^T q)[n]
    }
    prA[qq][n] = pp; prB[qq][n] = pq;
    __syncthreads();
    if (tid < 64) {
      const float np = prA[0][tid] + prA[1][tid] + prA[2][tid] + prA[3][tid];
      Pv[tid] = np; Pst[k][tid] = np;
      if (k <= KE) {
        const float nq = prB[0][tid] + prB[1][tid] + prB[2][tid] + prB[3][tid];
        Qv[tid] = nq; Qst[k][tid] = nq;
      }
    }
    __syncthreads();
  }
  const float dtc0 = dt;
  const float dtc1 = dt * dt * 0.5f;
  const float dtc2 = dtc1 * dt * (1.f / 3.f);
  const float dtc3 = dtc2 * dt * 0.25f;
  if (tid < 64) {
    dBs[tid] = dtc0 * Pst[0][tid] + dtc1 * Pst[1][tid] +
               dtc2 * Pst[2][tid] + dtc3 * Pst[3][tid];
#pragma unroll
    for (int k = 0; k <= KE; ++k) {
      Gk[(size_t)d * ((KE + 1) * 64) + k * 64 + tid] =
          dtc0 * Pst[k][tid] + dtc1 * Pst[k + 1][tid] +
          dtc2 * Pst[k + 2][tid] + dtc3 * Pst[k + 3][tid];
      Qk[(size_t)d * ((KE + 1) * 64) + k * 64 + tid] = Qst[k][tid];
    }
  }
  __syncthreads();
  if (tid < (KE + 1) * 16) {
    const int k = tid >> 4, seg = tid & 15;
    float s = 0.f;
#pragma unroll
    for (int i = 0; i < 4; ++i) s += Qst[k][seg * 4 + i] * dBs[seg * 4 + i];
    zp[k][seg] = s;
  }
  __syncthreads();
  if (tid <= KE) {
    float s = 0.f;
#pragma unroll
    for (int seg = 0; seg < 16; ++seg) s += zp[tid][seg];
    zs[tid] = s;
  }
  __syncthreads();
  if (tid < 64) {
    const float rdt = (float)tid * dt;
    float c = 1.f, acc = zs[0];
#pragma unroll
    for (int k = 1; k <= KE; ++k) { c *= rdt / (float)k; acc += c * zs[k]; }
    kloc[d * 64 + tid] = acc;
  }
  if (tid == 0) dts[d] = dt;
}

// Transpose x[b][t][d] -> xT[d][b][t]. 64x64 LDS tiles.
__global__ __launch_bounds__(256) void s4_xt(const float* __restrict__ x,
                                             float* __restrict__ xT) {
  __shared__ float tile[64][65];
  const int t0 = blockIdx.x * 64, d0 = blockIdx.y * 64, b = blockIdx.z;
  const int lt = threadIdx.x & 63, rq = threadIdx.x >> 6;
#pragma unroll
  for (int i = 0; i < 16; ++i) {
    const int row = rq + i * 4;
    tile[row][lt] = x[((size_t)b * Lz + t0 + row) * Dz + d0 + lt];
  }
  __syncthreads();
#pragma unroll
  for (int i = 0; i < 16; ++i) {
    const int row = rq + i * 4;
    xT[((size_t)(d0 + row) * Bz + b) * Lz + t0 + lt] = tile[lt][row];
  }
}

// Chunked state scan, one block per d. (No dynamic register-array indices!)
__global__ __launch_bounds__(256, 1) void s4_scan2(
    const float* __restrict__ xT, const float* __restrict__ Apow,
    const float* __restrict__ Gk, const float* __restrict__ dts,
    float* __restrict__ S) {
  __shared__ float As[Nz * SA];
  __shared__ float Gs[(KE + 1) * Nz];
  __shared__ float CT[KE + 1][66];
  __shared__ float Xs[8][64];
  __shared__ float Ss[8][64];
  const int d = blockIdx.x;
  const int tid = threadIdx.x, n = tid & 63, q = tid >> 6;
  const float dt = dts[d];
  if (tid < 65) {
    const float rdt = (float)tid * dt;
    float c = 1.f;
    CT[0][tid] = 1.f;
#pragma unroll
    for (int k = 1; k <= KE; ++k) { c *= rdt / (float)k; CT[k][tid] = c; }
  }
  for (int idx = tid; idx < (KE + 1) * 64; idx += 256)
    Gs[idx] = Gk[(size_t)d * ((KE + 1) * 64) + idx];
  __syncthreads();
  float arowE[64];   // arowE[m] = E64[n][m] - I[n][m]
#pragma unroll
  for (int m = 0; m < 64; ++m) arowE[m] = 0.f;
#pragma unroll 1
  for (int k = 1; k <= KE; ++k) {
#pragma unroll
    for (int i = 0; i < 4; ++i) {
      const int e = (tid + 256 * i) * 4;
      const int r = e >> 6, c = e & 63;
      const float4 v = *(const float4*)(Apow + (size_t)(k - 1) * 4096 + e);
      As[r * SA + c] = v.x; As[r * SA + c + 1] = v.y;
      As[r * SA + c + 2] = v.z; As[r * SA + c + 3] = v.w;
    }
    __syncthreads();
    const float ce = CT[k][64];   // (64 dt)^k / k!
#pragma unroll
    for (int m = 0; m < 64; ++m) arowE[m] = fmaf(ce, As[n * SA + m], arowE[m]);
    __syncthreads();
  }
  float arowU[64];
#pragma unroll
  for (int j = 0; j < 64; ++j) {
    float u = 0.f;
#pragma unroll
    for (int k = 0; k <= KE; ++k) u = fmaf(CT[k][63 - j], Gs[k * 64 + n], u);
    arowU[j] = u;                 // = (E^{63-j} dB)[n]
  }
  Ss[q][n] = 0.f;
  Ss[q + 4][n] = 0.f;
  __syncthreads();
  const float* xd = xT + (size_t)d * Bz * Lz;
  float* Sd = S + (size_t)d * (32 * 8 * 64);
#pragma unroll 1
  for (int c = 0; c < 32; ++c) {
    Xs[q][n]     = xd[(size_t)q * Lz + c * 64 + n];
    Xs[q + 4][n] = xd[(size_t)(q + 4) * Lz + c * 64 + n];
    Sd[c * 512 + q * 64 + n]       = Ss[q][n];
    Sd[c * 512 + (q + 4) * 64 + n] = Ss[q + 4][n];
    __syncthreads();
    float acc0 = Ss[q][n];        // E64 identity term (uniform LDS read)
    float acc1 = Ss[q + 4][n];
#pragma unroll
    for (int m = 0; m < 64; m += 4) {
      const float4 s0 = *(const float4*)&Ss[q][m];
      const float4 s1 = *(const float4*)&Ss[q + 4][m];
      const float4 x0 = *(const float4*)&Xs[q][m];
      const float4 x1 = *(const float4*)&Xs[q + 4][m];
      acc0 = fmaf(arowE[m], s0.x, acc0);     acc1 = fmaf(arowE[m], s1.x, acc1);
      acc0 = fmaf(arowE[m + 1], s0.y, acc0); acc1 = fmaf(arowE[m + 1], s1.y, acc1);
      acc0 = fmaf(arowE[m + 2], s0.z, acc0); acc1 = fmaf(arowE[m + 2], s1.z, acc1);
      acc0 = fmaf(arowE[m + 3], s0.w, acc0); acc1 = fmaf(arowE[m + 3], s1.w, acc1);
      acc0 = fmaf(arowU[m], x0.x, acc0);     acc1 = fmaf(arowU[m], x1.x, acc1);
      acc0 = fmaf(arowU[m + 1], x0.y, acc0); acc1 = fmaf(arowU[m + 1], x1.y, acc1);
      acc0 = fmaf(arowU[m + 2], x0.z, acc0); acc1 = fmaf(arowU[m + 2], x1.z, acc1);
      acc0 = fmaf(arowU[m + 3], x0.w, acc0); acc1 = fmaf(arowU[m + 3], x1.w, acc1);
    }
    __syncthreads();
    Ss[q][n] = acc0;
    Ss[q + 4][n] = acc1;
    __syncthreads();
  }
}

// Output as LDS-tiled GEMM (no big per-thread arrays -> nothing to spill):
// per d:  y(64 x 256) = [W | T](64 x 128) . [S ; X](128 x 256)
//   W[r][m] = (C^T E^{r+1})[m] (from Qk+CT), T[r][j] = k[r-j] (Toeplitz)
// Microtile 4x4: rows r = tr*4+i, cols col = tc+16*jj (spacing 1 -> 2-way LDS).
__global__ __launch_bounds__(256, 1) void s4_out3(
    const float* __restrict__ xT, const float* __restrict__ S,
    const float* __restrict__ Qk, const float* __restrict__ kloc,
    const float* __restrict__ dts, float* __restrict__ yT) {
  __shared__ alignas(16) float Ms[64 * SM];   // [r][k]  k<64: W, k>=64: T
  __shared__ alignas(16) float Zs[64 * SM];   // [col][k] k<64: S, k>=64: X
  __shared__ float Qs[(KE + 1) * Nz];
  __shared__ float CT[KE + 1][66];
  __shared__ float kx[64];
  const int d = blockIdx.x;
  const int tid = threadIdx.x;
  const int tc = tid & 15, tr = tid >> 4;
  const float dt = dts[d];
  if (tid < 65) {
    const float rdt = (float)tid * dt;
    float c = 1.f;
    CT[0][tid] = 1.f;
#pragma unroll
    for (int k = 1; k <= KE; ++k) { c *= rdt / (float)k; CT[k][tid] = c; }
  }
  for (int idx = tid; idx < (KE + 1) * 64; idx += 256)
    Qs[idx] = Qk[(size_t)d * ((KE + 1) * 64) + idx];
  if (tid < 64) kx[tid] = kloc[d * 64 + tid];
  __syncthreads();
  // build Ms: W part (each entry: 9-term Horner over Qs) and Toeplitz part
#pragma unroll
  for (int i = 0; i < 16; ++i) {
    const int e = tid + 256 * i;
    const int r = e >> 6, m = e & 63;
    float w = 0.f;
#pragma unroll
    for (int k = 0; k <= KE; ++k) w = fmaf(CT[k][r + 1], Qs[k * 64 + m], w);
    Ms[r * SM + m] = w;
  }
#pragma unroll
  for (int i = 0; i < 16; ++i) {
    const int e = tid + 256 * i;
    const int r = e >> 6, j = e & 63;
    Ms[r * SM + 64 + j] = (j <= r) ? kx[r - j] : 0.f;
  }
  const float* xd = xT + (size_t)d * Bz * Lz;
  const float* Sd = S + (size_t)d * (32 * 8 * 64);
  float* yd = yT + (size_t)d * Bz * Lz;
  const int lcol = tid >> 2, seg = tid & 3;        // staging/writeback roles
  const int sbb = lcol & 7, sccl = lcol >> 3;
#pragma unroll 1
  for (int ch = 0; ch < 4; ++ch) {
    // stage Z = [S ; X] for 64 columns (col = ccl*8 + bb, cc = ch*8+ccl)
    {
      const int cc = ch * 8 + sccl;
      const float* sp = Sd + cc * 512 + sbb * 64 + seg * 16;
      const float* xp = xd + (size_t)sbb * Lz + cc * 64 + seg * 16;
      float* zrow = Zs + lcol * SM;
#pragma unroll
      for (int i = 0; i < 4; ++i) {
        *(float4*)(zrow + seg * 16 + i * 4) = *(const float4*)(sp + i * 4);
        *(float4*)(zrow + 64 + seg * 16 + i * 4) = *(const float4*)(xp + i * 4);
      }
    }
    __syncthreads();
    float acc[16];
#pragma unroll
    for (int i = 0; i < 16; ++i) acc[i] = 0.f;
#pragma unroll 4
    for (int k = 0; k < 128; k += 4) {
      float4 mv[4], zv[4];
#pragma unroll
      for (int i = 0; i < 4; ++i)
        mv[i] = *(const float4*)&Ms[(tr * 4 + i) * SM + k];
#pragma unroll
      for (int jj = 0; jj < 4; ++jj)
        zv[jj] = *(const float4*)&Zs[(tc + 16 * jj) * SM + k];
#pragma unroll
      for (int i = 0; i < 4; ++i)
#pragma unroll
        for (int jj = 0; jj < 4; ++jj) {
          acc[i * 4 + jj] = fmaf(mv[i].x, zv[jj].x, acc[i * 4 + jj]);
          acc[i * 4 + jj] = fmaf(mv[i].y, zv[jj].y, acc[i * 4 + jj]);
          acc[i * 4 + jj] = fmaf(mv[i].z, zv[jj].z, acc[i * 4 + jj]);
          acc[i * 4 + jj] = fmaf(mv[i].w, zv[jj].w, acc[i * 4 + jj]);
        }
    }
    __syncthreads();             // done reading Zs; reuse it as y staging
#pragma unroll
    for (int i = 0; i < 4; ++i)
#pragma unroll
      for (int jj = 0; jj < 4; ++jj)
        Zs[(tc + 16 * jj) * SM + tr * 4 + i] = acc[i * 4 + jj];
    __syncthreads();
    // coalesced writeback: 64 rows contiguous per column
    {
      const int cc = ch * 8 + sccl;
      float* yp = yd + (size_t)sbb * Lz + cc * 64 + seg * 16;
      const float* zrow = Zs + lcol * SM;
#pragma unroll
      for (int i = 0; i < 4; ++i)
        *(float4*)(yp + i * 4) = *(const float4*)(zrow + seg * 16 + i * 4);
    }
    __syncthreads();             // before next chunk overwrites Zs
  }
}

// out[row,c] = sum_d (yT[d][row] + x[row,d]*skip[d]) * W[c,d] + b[c]
__global__ __launch_bounds__(256) void s4_gemm(
    const float* __restrict__ yT, const float* __restrict__ x,
    const float* __restrict__ skip_D, const float* __restrict__ Wo,
    const float* __restrict__ bo, float* __restrict__ out) {
  __shared__ alignas(16) float Ys[64 * 17];
  __shared__ alignas(16) float Ws[64 * 17];
  const int tid = threadIdx.x;
  const int r0 = blockIdx.x * 64;
  const int c0 = blockIdx.y * 64;
  const int brow = r0 >> 11;
  const int t0 = r0 & 2047;
  const int tr = tid >> 4, tc = tid & 15;
  const int lr = tid >> 2, lq = tid & 3;
  float acc[16];
#pragma unroll
  for (int i = 0; i < 16; ++i) acc[i] = 0.f;
  for (int kc = 0; kc < 16; ++kc) {
    const int dc0 = kc * 16;
    const float4 xa = *(const float4*)(x + (size_t)(r0 + lr) * Dz + dc0 + lq * 4);
    const float4 sk = *(const float4*)(skip_D + dc0 + lq * 4);
    const float4 wa = *(const float4*)(Wo + (size_t)(c0 + lr) * Dz + dc0 + lq * 4);
    float yv[4];
#pragma unroll
    for (int i = 0; i < 4; ++i) {
      const int dd = dc0 + lq * 4 + i;
      yv[i] = yT[((size_t)dd * Bz + brow) * Lz + t0 + lr];
    }
    Ys[lr * 17 + lq * 4 + 0] = yv[0] + xa.x * sk.x;
    Ys[lr * 17 + lq * 4 + 1] = yv[1] + xa.y * sk.y;
    Ys[lr * 17 + lq * 4 + 2] = yv[2] + xa.z * sk.z;
    Ys[lr * 17 + lq * 4 + 3] = yv[3] + xa.w * sk.w;
    Ws[lr * 17 + lq * 4 + 0] = wa.x; Ws[lr * 17 + lq * 4 + 1] = wa.y;
    Ws[lr * 17 + lq * 4 + 2] = wa.z; Ws[lr * 17 + lq * 4 + 3] = wa.w;
    __syncthreads();
#pragma unroll
    for (int dk = 0; dk < 16; ++dk) {
      float yvv[4], wv[4];
#pragma unroll
      for (int i = 0; i < 4; ++i) yvv[i] = Ys[(tr * 4 + i) * 17 + dk];
#pragma unroll
      for (int i = 0; i < 4; ++i) wv[i] = Ws[(tc * 4 + i) * 17 + dk];
#pragma unroll
      for (int i = 0; i < 4; ++i)
#pragma unroll
        for (int jj = 0; jj < 4; ++jj)
          acc[i * 4 + jj] = fmaf(yvv[i], wv[jj], acc[i * 4 + jj]);
    }
    __syncthreads();
  }
#pragma unroll
  for (int i = 0; i < 4; ++i)
#pragma unroll
    for (int jj = 0; jj < 4; ++jj) {
      const int cc = c0 + tc * 4 + jj;
      out[(size_t)(r0 + tr * 4 + i) * Dz + cc] = acc[i * 4 + jj] + bo[cc];
    }
}

extern "C" void kernel_launch(void* const* d_in, const int* in_sizes, int n_in,
                              void* d_out, int out_size, void* d_ws, size_t ws_size,
                              hipStream_t stream) {
  const float* x         = (const float*)d_in[0];
  const float* log_A     = (const float*)d_in[1];
  const float* Bp        = (const float*)d_in[2];
  const float* Cp        = (const float*)d_in[3];
  const float* log_delta = (const float*)d_in[4];
  const float* skip_D    = (const float*)d_in[5];
  const float* W_out     = (const float*)d_in[6];
  const float* b_out     = (const float*)d_in[7];
  float* out = (float*)d_out;

  float* xT   = (float*)d_ws;
  float* yT   = xT + (size_t)Dz * Bz * Lz;
  float* S    = yT + (size_t)Dz * Bz * Lz;
  float* Apow = S + (size_t)Dz * (32 * 8 * 64);
  float* Gk   = Apow + (size_t)8 * 4096;
  float* Qk   = Gk + (size_t)Dz * (KE + 1) * 64;
  float* kloc = Qk + (size_t)Dz * (KE + 1) * 64;
  float* dts  = kloc + (size_t)Dz * 64;

  hipLaunchKernelGGL(s4_xt, dim3(Lz / 64, Dz / 64, Bz), dim3(256), 0, stream,
                     x, xT);
  hipLaunchKernelGGL(s4_powinit, dim3(16), dim3(256), 0, stream, log_A, Apow);
  hipLaunchKernelGGL(s4_powmm, dim3(1), dim3(256), 0, stream, Apow, Apow, 0, 1);
  hipLaunchKernelGGL(s4_powmm, dim3(2), dim3(256), 0, stream, Apow, Apow, 1, 2);
  hipLaunchKernelGGL(s4_powmm, dim3(4), dim3(256), 0, stream, Apow, Apow, 3, 4);
  hipLaunchKernelGGL(s4_build2, dim3(Dz), dim3(256), 0, stream,
                     Apow, Bp, Cp, log_delta, Gk, Qk, kloc, dts);
  hipLaunchKernelGGL(s4_scan2, dim3(Dz), dim3(256), 0, stream,
                     xT, Apow, Gk, dts, S);
  hipLaunchKernelGGL(s4_out3, dim3(Dz), dim3(256), 0, stream,
                     xT, S, Qk, kloc, dts, yT);
  hipLaunchKernelGGL(s4_gemm, dim3((Bz * Lz) / 64, Dz / 64), dim3(256), 0, stream,
                     yT, x, skip_D, W_out, b_out, out);
}